// Round 1
// baseline (20421.387 us; speedup 1.0000x reference)
//
#include <hip/hip_runtime.h>

typedef unsigned short UST;
typedef unsigned int uint32;
typedef float f32x4 __attribute__((ext_vector_type(4)));
typedef short s16x8 __attribute__((ext_vector_type(8)));

// problem sizes
// L=512 B=128 D=512 T=200 E=384 C=128 H=512 V=46

__device__ __forceinline__ float b2f(UST u) {
  uint32 x = ((uint32)u) << 16;
  union { uint32 u; float f; } v; v.u = x; return v.f;
}
__device__ __forceinline__ UST f2bf(float f) {
  union { float f; uint32 u; } v; v.f = f;
  uint32 r = (v.u + 0x7fffu + ((v.u >> 16) & 1u)) >> 16;
  return (UST)r;
}
__device__ __forceinline__ ushort4 f2bf4(float4 v) {
  ushort4 r; r.x = f2bf(v.x); r.y = f2bf(v.y); r.z = f2bf(v.z); r.w = f2bf(v.w); return r;
}
__device__ __forceinline__ float sigf(float x) { return 1.f / (1.f + __expf(-x)); }
__device__ __forceinline__ float tanhf_(float x) { return 2.f / (1.f + __expf(-2.f * x)) - 1.f; }

struct Args {
  const float* lf; const int* ulen; const int* tr; const float* emb;
  const float* wih0; const float* whh0; const float* bih0; const float* bhh0;
  const float* wih1; const float* whh1; const float* bih1; const float* bhh1;
  const float* wih2; const float* whh2; const float* bih2; const float* bhh2;
  const float* phi_w; const float* phi_b; const float* key_w; const float* key_b;
  const float* val_w; const float* val_b; const float* out_w; const float* out_b;
  const float* ihx0; const float* icx0; const float* ihx1; const float* icx1;
  const float* ihx2; const float* icx2;
  int* bar; UST* wr; UST* xemb; UST* phi_bf; UST* keyfT; UST* valfT;
  UST* hx0; UST* hx1; UST* hx2; UST* ctx; UST* h2h; UST* cxh;
  float* out_logits; float* out_attn;
};

// ---------------- P1: zero barrier, swizzle weights to bf16 (row=j*4+g, k), build xemb, phi_bf
__global__ void __launch_bounds__(256) kprep(Args A) {
  const long N0 = 10240;            // barrier ints (40960 B)
  const long N1 = 3L * 2048 * 1024; // reordered weights
  const long N2 = 200L * 128 * 384; // xemb
  const long N3 = 128L * 512;       // phi
  long total = N0 + N1 + N2 + N3;
  long stride = (long)gridDim.x * blockDim.x;
  for (long i = (long)blockIdx.x * 256 + threadIdx.x; i < total; i += stride) {
    long j = i;
    if (j < N0) { A.bar[j] = 0; continue; }
    j -= N0;
    if (j < N1) {
      int cell = (int)(j >> 21); int r = (int)(j & 2097151); int row = r >> 10; int k = r & 1023;
      int jc = row >> 2, g = row & 3;
      const float* wi = cell == 0 ? A.wih0 : cell == 1 ? A.wih1 : A.wih2;
      const float* wh = cell == 0 ? A.whh0 : cell == 1 ? A.whh1 : A.whh2;
      float v = (k < 512) ? wi[(g * 512 + jc) * 512 + k] : wh[(g * 512 + jc) * 512 + k - 512];
      A.wr[j] = f2bf(v);
      continue;
    }
    j -= N1;
    if (j < N2) {
      int t = (int)(j / 49152); int r = (int)(j % 49152); int bb = r / 384; int e = r - bb * 384;
      int ch = (t == 0) ? 0 : A.tr[(t - 1) * 128 + bb];
      A.xemb[j] = f2bf(A.emb[ch * 384 + e]);
      continue;
    }
    j -= N2;
    A.phi_bf[j] = f2bf(A.phi_w[j]);
  }
}

// ---------------- P2: keyfT/valfT = (lf . W^T + b), stored [B][C][L] bf16 (transposed)
__global__ void __launch_bounds__(256) kkv(Args A) {
  __shared__ __attribute__((aligned(16))) char sm[17408 + 34816];
  UST (*A_lds)[136] = (UST(*)[136])sm;
  UST (*W_lds)[136] = (UST(*)[136])(sm + 17408);
  float* sbuf = (float*)(sm + 17408); // alias: reuse after K-loop
  int tid = threadIdx.x, lane = tid & 63, wv = tid >> 6, ln = lane & 15, qd = lane >> 4;
  int blk = blockIdx.x;
  int b = blk >> 4, lt = (blk >> 1) & 7, kv = blk & 1;
  int l0 = lt * 64;
  const float* W = kv ? A.val_w : A.key_w;
  const float* bs = kv ? A.val_b : A.key_b;
  UST* outp = kv ? A.valfT : A.keyfT;
  f32x4 acc[8];
#pragma unroll
  for (int nt = 0; nt < 8; ++nt) {
    float x = bs[nt * 16 + ln];
    f32x4 t; t[0] = x; t[1] = x; t[2] = x; t[3] = x; acc[nt] = t;
  }
  for (int cc = 0; cc < 4; ++cc) {
    int d0 = cc * 128;
#pragma unroll
    for (int it = 0; it < 8; ++it) { // A tile: 64 rows x 128 d
      int idx = it * 256 + tid, row = idx >> 5, seg = idx & 31;
      float4 v = *(const float4*)(A.lf + ((size_t)(l0 + row) * 128 + b) * 512 + d0 + seg * 4);
      *(ushort4*)&A_lds[row][seg * 4] = f2bf4(v);
    }
#pragma unroll
    for (int it = 0; it < 16; ++it) { // W tile: 128 rows x 128 d
      int idx = it * 256 + tid, row = idx >> 5, seg = idx & 31;
      float4 v = *(const float4*)(W + (size_t)row * 512 + d0 + seg * 4);
      *(ushort4*)&W_lds[row][seg * 4] = f2bf4(v);
    }
    __syncthreads();
#pragma unroll
    for (int ks = 0; ks < 4; ++ks) {
      s16x8 av = *(const s16x8*)&A_lds[wv * 16 + ln][ks * 32 + qd * 8];
#pragma unroll
      for (int nt = 0; nt < 8; ++nt) {
        s16x8 bv = *(const s16x8*)&W_lds[nt * 16 + ln][ks * 32 + qd * 8];
        acc[nt] = __builtin_amdgcn_mfma_f32_16x16x32_bf16(av, bv, acc[nt], 0, 0, 0);
      }
    }
    __syncthreads();
  }
  // stage O[l_local][c] then write transposed [B][C][L]
#pragma unroll
  for (int nt = 0; nt < 8; ++nt)
#pragma unroll
    for (int r = 0; r < 4; ++r)
      sbuf[(wv * 16 + qd * 4 + r) * 128 + nt * 16 + ln] = acc[nt][r];
  __syncthreads();
  int c2 = tid >> 1, lh = tid & 1;
  for (int g8 = 0; g8 < 4; ++g8) {
    UST tmp[8];
#pragma unroll
    for (int i = 0; i < 8; ++i) tmp[i] = f2bf(sbuf[(lh * 32 + g8 * 8 + i) * 128 + c2]);
    *(uint4*)(outp + ((size_t)b * 128 + c2) * 512 + l0 + lh * 32 + g8 * 8) = *(uint4*)tmp;
  }
}

// ---------------- grid barrier: flag per block + gen; relaxed spins, one acquire at exit
__device__ __forceinline__ void gbar(int* bar, int epoch, int tid) {
  __syncthreads();
  if (blockIdx.x == 0) {
    if (tid >= 1 && tid < 256) {
      while (__hip_atomic_load(&bar[tid * 32], __ATOMIC_RELAXED, __HIP_MEMORY_SCOPE_AGENT) < epoch)
        __builtin_amdgcn_s_sleep(2);
    }
    __syncthreads();
    if (tid == 0)
      __hip_atomic_store(&bar[8192], epoch, __ATOMIC_RELEASE, __HIP_MEMORY_SCOPE_AGENT);
  } else {
    if (tid == 0)
      __hip_atomic_store(&bar[blockIdx.x * 32], epoch, __ATOMIC_RELEASE, __HIP_MEMORY_SCOPE_AGENT);
  }
  if (tid == 0) {
    while (__hip_atomic_load(&bar[8192], __ATOMIC_RELAXED, __HIP_MEMORY_SCOPE_AGENT) < epoch)
      __builtin_amdgcn_s_sleep(2);
    (void)__hip_atomic_load(&bar[8192], __ATOMIC_ACQUIRE, __HIP_MEMORY_SCOPE_AGENT);
  }
  __syncthreads();
}

// ---------------- LSTM cell phase (blocks 0..127). m=blk&1 (row half), js=blk>>1 (8 h-cols)
__device__ __forceinline__ void cell_phase(const Args& A, int cell, int t, int p, int po,
    int m, int js, int j0, int wv, int lane, int ln, int qd, int tid,
    UST (*x_lds)[136], UST (*w_lds)[136], float (*creg)[4], const float* biasv) {
  const UST* wrbase = A.wr + (size_t)cell * 2097152 + (size_t)js * 32 * 1024;
  f32x4 acc0; acc0[0] = 0; acc0[1] = 0; acc0[2] = 0; acc0[3] = 0;
  f32x4 acc1 = acc0;
  const UST* sa; const UST* sc = nullptr;
  if (cell == 0)      { sa = A.hx0 + po * 65536; }
  else if (cell == 1) { sa = A.hx0 + p * 65536; sc = A.hx1 + po * 65536; }
  else                { sa = A.hx1 + p * 65536; sc = A.hx2 + po * 65536; }
  const UST* xe = A.xemb + (size_t)t * 49152;
  const UST* cx = A.ctx + po * 16384;
  for (int cc = 0; cc < 8; ++cc) {
    int k0 = cc * 128;
#pragma unroll
    for (int it = 0; it < 2; ++it) { // weights: 32 rows x 128 k
      int idx = it * 256 + tid, row = idx >> 4, seg = idx & 15;
      uint4 v = *(const uint4*)(wrbase + row * 1024 + k0 + seg * 8);
      *(uint4*)&w_lds[row][seg * 8] = v;
    }
#pragma unroll
    for (int it = 0; it < 4; ++it) { // x: 64 rows x 128 k
      int idx = it * 256 + tid, row = idx >> 4, seg = idx & 15;
      int grow = m * 64 + row;
      const UST* src; int kk;
      if (cell == 0) {
        if (cc < 3)       { src = xe + grow * 384; kk = k0; }
        else if (cc == 3) { src = cx + grow * 128; kk = 0; }
        else              { src = sa + grow * 512; kk = k0 - 512; }
      } else {
        if (cc < 4) { src = sa + grow * 512; kk = k0; }
        else        { src = sc + grow * 512; kk = k0 - 512; }
      }
      uint4 v = *(const uint4*)(src + kk + seg * 8);
      *(uint4*)&x_lds[row][seg * 8] = v;
    }
    __syncthreads();
#pragma unroll
    for (int ks = 0; ks < 4; ++ks) {
      s16x8 av = *(const s16x8*)&x_lds[wv * 16 + ln][ks * 32 + qd * 8];
      s16x8 b0 = *(const s16x8*)&w_lds[ln][ks * 32 + qd * 8];
      s16x8 b1 = *(const s16x8*)&w_lds[16 + ln][ks * 32 + qd * 8];
      acc0 = __builtin_amdgcn_mfma_f32_16x16x32_bf16(av, b0, acc0, 0, 0, 0);
      acc1 = __builtin_amdgcn_mfma_f32_16x16x32_bf16(av, b1, acc1, 0, 0, 0);
    }
    __syncthreads();
  }
  UST* hout = (cell == 0 ? A.hx0 : cell == 1 ? A.hx1 : A.hx2) + p * 65536;
#pragma unroll
  for (int nt = 0; nt < 2; ++nt) {
    f32x4 av = nt ? acc1 : acc0;
    float bsv = biasv[nt];
#pragma unroll
    for (int r = 0; r < 4; ++r) {
      float gv = av[r] + bsv;
      int base = lane & ~3;
      float gi = __shfl(gv, base);
      float gf = __shfl(gv, base | 1);
      float gg = __shfl(gv, base | 2);
      float go = __shfl(gv, base | 3);
      if ((lane & 3) == 0) {
        float cn = sigf(gf) * creg[nt][r] + sigf(gi) * tanhf_(gg);
        float h = sigf(go) * tanhf_(cn);
        creg[nt][r] = cn;
        int row = m * 64 + wv * 16 + qd * 4 + r;
        int col = j0 + nt * 4 + (ln >> 2);
        UST hb = f2bf(h);
        hout[row * 512 + col] = hb;
        if (cell == 2) A.h2h[((size_t)t * 128 + row) * 512 + col] = hb;
      }
    }
  }
}

// ---------------- attention phase (blocks 128..255, one batch row each)
__device__ __forceinline__ void attend(const Args& A, int t, int p, int b,
    int tid, int lane, int wv,
    float* att_h, float* att_q, float (*e_part)[512], float* att_red) {
  const UST* hx2p = A.hx2 + p * 65536;
  for (int i = tid; i < 512; i += 256) att_h[i] = b2f(hx2p[b * 512 + i]);
  __syncthreads();
  int c = tid & 127, half = tid >> 7;
  { // q = phi_b + phi . hx2
    float acc = half ? 0.f : A.phi_b[c];
    const UST* pr = A.phi_bf + c * 512 + half * 256;
    const float* hh = att_h + half * 256;
#pragma unroll 4
    for (int k = 0; k < 256; k += 8) {
      uint4 v = *(const uint4*)(pr + k);
      const UST* us = (const UST*)&v;
#pragma unroll
      for (int i = 0; i < 8; ++i) acc += b2f(us[i]) * hh[k + i];
    }
    att_q[tid] = acc;
  }
  __syncthreads();
  if (tid < 128) att_q[tid] += att_q[tid + 128];
  __syncthreads();
  { // energies: thread (cg=tid>>6, lg=tid&63) covers 8 l's over 32 c's
    int cg = tid >> 6, lg = tid & 63;
    float ep[8] = {0, 0, 0, 0, 0, 0, 0, 0};
    const UST* kb = A.keyfT + (size_t)b * 65536 + lg * 8;
#pragma unroll 4
    for (int c2 = cg * 32; c2 < cg * 32 + 32; ++c2) {
      uint4 v = *(const uint4*)(kb + (size_t)c2 * 512);
      const UST* us = (const UST*)&v;
      float qv = att_q[c2];
#pragma unroll
      for (int i = 0; i < 8; ++i) ep[i] += qv * b2f(us[i]);
    }
#pragma unroll
    for (int i = 0; i < 8; ++i) e_part[cg][lg * 8 + i] = ep[i];
  }
  __syncthreads();
  float e0 = e_part[0][2 * tid] + e_part[1][2 * tid] + e_part[2][2 * tid] + e_part[3][2 * tid];
  float e1 = e_part[0][2 * tid + 1] + e_part[1][2 * tid + 1] + e_part[2][2 * tid + 1] + e_part[3][2 * tid + 1];
  float mx = fmaxf(e0, e1);
#pragma unroll
  for (int off = 32; off; off >>= 1) mx = fmaxf(mx, __shfl_xor(mx, off));
  if (lane == 0) att_red[wv] = mx;
  __syncthreads();
  mx = fmaxf(fmaxf(att_red[0], att_red[1]), fmaxf(att_red[2], att_red[3]));
  int len = A.ulen[b];
  float x0 = (2 * tid < len) ? __expf(e0 - mx) : 0.f;
  float x1 = (2 * tid + 1 < len) ? __expf(e1 - mx) : 0.f;
  float s = x0 + x1;
#pragma unroll
  for (int off = 32; off; off >>= 1) s += __shfl_xor(s, off);
  if (lane == 0) att_red[8 + wv] = s;
  __syncthreads();
  s = att_red[8] + att_red[9] + att_red[10] + att_red[11];
  float inv = 1.f / fmaxf(s, 1e-12f);
  float a0 = x0 * inv, a1 = x1 * inv;
  float* esm = &e_part[0][0];
  esm[2 * tid] = a0; esm[2 * tid + 1] = a1;
  if (t >= 0) {
    float2 st; st.x = a0; st.y = a1;
    *(float2*)(A.out_attn + ((size_t)t * 128 + b) * 512 + 2 * tid) = st;
  }
  __syncthreads();
  { // ctx[c] = sum_l a_l * valfT[b][c][l]
    float acc = 0.f;
    const UST* vb = A.valfT + (size_t)b * 65536 + (size_t)c * 512 + half * 256;
    const float* aa = esm + half * 256;
#pragma unroll 4
    for (int k = 0; k < 256; k += 8) {
      uint4 v = *(const uint4*)(vb + k);
      const UST* us = (const UST*)&v;
#pragma unroll
      for (int i = 0; i < 8; ++i) acc += aa[k + i] * b2f(us[i]);
    }
    att_q[tid] = acc;
  }
  __syncthreads();
  if (tid < 128) {
    float cv = att_q[tid] + att_q[tid + 128];
    UST cb = f2bf(cv);
    A.ctx[p * 16384 + b * 128 + tid] = cb;
    if (t >= 0) A.cxh[((size_t)t * 128 + b) * 128 + tid] = cb;
  }
}

// ---------------- main persistent cooperative kernel
__global__ void __launch_bounds__(256) kmain(Args A) {
  __shared__ UST x_lds[64][136];
  __shared__ UST w_lds[32][136];
  __shared__ float att_h[512];
  __shared__ float att_q[256];
  __shared__ float e_part[4][512];
  __shared__ float att_red[16];
  int blk = blockIdx.x, tid = threadIdx.x;
  int lane = tid & 63, wv = tid >> 6, ln = lane & 15, qd = lane >> 4;
  bool isCell = blk < 128;
  int m = blk & 1, js = blk >> 1, j0 = (blk >> 1) * 8;
  int b = blk - 128;
  float creg[3][2][4];
  float biasv[3][2];
  if (isCell) {
    const float* bihA[3] = {A.bih0, A.bih1, A.bih2};
    const float* bhhA[3] = {A.bhh0, A.bhh1, A.bhh2};
    const float* icxA[3] = {A.icx0, A.icx1, A.icx2};
    const float* ihxA[3] = {A.ihx0, A.ihx1, A.ihx2};
    UST* hxA[3] = {A.hx0, A.hx1, A.hx2};
#pragma unroll
    for (int cI = 0; cI < 3; ++cI) {
#pragma unroll
      for (int nt = 0; nt < 2; ++nt) {
        int g = ln & 3, jl = j0 + nt * 4 + (ln >> 2);
        biasv[cI][nt] = bihA[cI][g * 512 + jl] + bhhA[cI][g * 512 + jl];
        float cv = icxA[cI][jl];
#pragma unroll
        for (int r = 0; r < 4; ++r) creg[cI][nt][r] = cv;
      }
      for (int i = tid; i < 512; i += 256) { // init hx[1] patch (rows m*64.., cols j0..j0+7)
        int row = i >> 3, cc = i & 7;
        hxA[cI][65536 + (m * 64 + row) * 512 + j0 + cc] = f2bf(ihxA[cI][j0 + cc]);
      }
    }
  }
  int epoch = 0;
  gbar(A.bar, ++epoch, tid);
  if (!isCell) attend(A, -1, 1, b, tid, lane, wv, att_h, att_q, e_part, att_red);
  gbar(A.bar, ++epoch, tid);
  for (int t = 0; t < 200; ++t) {
    int p = t & 1, po = p ^ 1;
    if (isCell) cell_phase(A, 0, t, p, po, m, js, j0, wv, lane, ln, qd, tid, x_lds, w_lds, creg[0], biasv[0]);
    gbar(A.bar, ++epoch, tid);
    if (isCell) cell_phase(A, 1, t, p, po, m, js, j0, wv, lane, ln, qd, tid, x_lds, w_lds, creg[1], biasv[1]);
    gbar(A.bar, ++epoch, tid);
    if (isCell) cell_phase(A, 2, t, p, po, m, js, j0, wv, lane, ln, qd, tid, x_lds, w_lds, creg[2], biasv[2]);
    gbar(A.bar, ++epoch, tid);
    if (!isCell) attend(A, t, p, b, tid, lane, wv, att_h, att_q, e_part, att_red);
    gbar(A.bar, ++epoch, tid);
  }
}

// ---------------- epilogue: logits[t,b,v] = [hx2,ctx] . out_w^T + out_b
__global__ void __launch_bounds__(256) kepi(Args A) {
  __shared__ UST ow[46 * 648];
  __shared__ float ob[46];
  int t = blockIdx.x, tid = threadIdx.x;
  for (int i = tid; i < 46 * 640; i += 256) { int v = i / 640, k = i - v * 640; ow[v * 648 + k] = f2bf(A.out_w[i]); }
  if (tid < 46) ob[tid] = A.out_b[tid];
  __syncthreads();
  for (int oi = tid; oi < 128 * 46; oi += 256) {
    int bb = oi / 46, v = oi - bb * 46;
    const UST* xh = A.h2h + ((size_t)t * 128 + bb) * 512;
    const UST* xc = A.cxh + ((size_t)t * 128 + bb) * 128;
    const UST* wrow = &ow[v * 648];
    float acc = ob[v];
    for (int k = 0; k < 512; k += 8) {
      uint4 xv = *(const uint4*)(xh + k);
      uint4 wv4 = *(const uint4*)(wrow + k);
      const UST* xs = (const UST*)&xv; const UST* wl = (const UST*)&wv4;
#pragma unroll
      for (int i = 0; i < 8; ++i) acc += b2f(xs[i]) * b2f(wl[i]);
    }
    for (int k = 0; k < 128; k += 8) {
      uint4 xv = *(const uint4*)(xc + k);
      uint4 wv4 = *(const uint4*)(wrow + 512 + k);
      const UST* xs = (const UST*)&xv; const UST* wl = (const UST*)&wv4;
#pragma unroll
      for (int i = 0; i < 8; ++i) acc += b2f(xs[i]) * b2f(wl[i]);
    }
    A.out_logits[((size_t)t * 128 + bb) * 46 + v] = acc;
  }
}

extern "C" void kernel_launch(void* const* d_in, const int* in_sizes, int n_in,
                              void* d_out, int out_size, void* d_ws, size_t ws_size,
                              hipStream_t stream) {
  (void)in_sizes; (void)n_in; (void)out_size; (void)ws_size;
  Args a;
  a.lf = (const float*)d_in[0]; a.ulen = (const int*)d_in[1]; a.tr = (const int*)d_in[2];
  a.emb = (const float*)d_in[3];
  a.wih0 = (const float*)d_in[4]; a.whh0 = (const float*)d_in[5]; a.bih0 = (const float*)d_in[6]; a.bhh0 = (const float*)d_in[7];
  a.wih1 = (const float*)d_in[8]; a.whh1 = (const float*)d_in[9]; a.bih1 = (const float*)d_in[10]; a.bhh1 = (const float*)d_in[11];
  a.wih2 = (const float*)d_in[12]; a.whh2 = (const float*)d_in[13]; a.bih2 = (const float*)d_in[14]; a.bhh2 = (const float*)d_in[15];
  a.phi_w = (const float*)d_in[16]; a.phi_b = (const float*)d_in[17];
  a.key_w = (const float*)d_in[18]; a.key_b = (const float*)d_in[19];
  a.val_w = (const float*)d_in[20]; a.val_b = (const float*)d_in[21];
  a.out_w = (const float*)d_in[22]; a.out_b = (const float*)d_in[23];
  a.ihx0 = (const float*)d_in[24]; a.icx0 = (const float*)d_in[25];
  a.ihx1 = (const float*)d_in[26]; a.icx1 = (const float*)d_in[27];
  a.ihx2 = (const float*)d_in[28]; a.icx2 = (const float*)d_in[29];
  char* ws = (char*)d_ws;
  a.bar    = (int*)ws;                   // 40,960 B
  a.wr     = (UST*)(ws + 40960);         // 12,582,912 B
  a.xemb   = (UST*)(ws + 12623872);      // 19,660,800 B
  a.phi_bf = (UST*)(ws + 32284672);      // 131,072 B
  a.keyfT  = (UST*)(ws + 32415744);      // 16,777,216 B
  a.valfT  = (UST*)(ws + 49192960);      // 16,777,216 B
  a.hx0    = (UST*)(ws + 65970176);      // 262,144 B (2 bufs)
  a.hx1    = (UST*)(ws + 66232320);      // 262,144 B
  a.hx2    = (UST*)(ws + 66494464);      // 262,144 B
  a.ctx    = (UST*)(ws + 66756608);      // 65,536 B (2 bufs)
  a.h2h    = (UST*)(ws + 66822144);      // 26,214,400 B
  a.cxh    = (UST*)(ws + 93036544);      // 6,553,600 B  -> total 99,590,144 B
  a.out_logits = (float*)d_out;
  a.out_attn   = (float*)d_out + 1177600;
  kprep<<<4096, 256, 0, stream>>>(a);
  kkv<<<2048, 256, 0, stream>>>(a);
  void* kp[] = { (void*)&a };
  hipLaunchCooperativeKernel((void*)kmain, dim3(256), dim3(256), kp, 0, stream);
  kepi<<<200, 256, 0, stream>>>(a);
}

// Round 5
// 10236.486 us; speedup vs baseline: 1.9950x; 1.9950x over previous
//
#include <hip/hip_runtime.h>

typedef unsigned short UST;
typedef unsigned int uint32;
typedef float f32x4 __attribute__((ext_vector_type(4)));
typedef short s16x8 __attribute__((ext_vector_type(8)));

// problem sizes: L=512 B=128 D=512 T=200 E=384 C=128 H=512 V=46

__device__ __forceinline__ float b2f(UST u) {
  uint32 x = ((uint32)u) << 16;
  union { uint32 u; float f; } v; v.u = x; return v.f;
}
__device__ __forceinline__ UST f2bf(float f) {
  union { float f; uint32 u; } v; v.f = f;
  uint32 r = (v.u + 0x7fffu + ((v.u >> 16) & 1u)) >> 16;
  return (UST)r;
}
__device__ __forceinline__ ushort4 f2bf4(float4 v) {
  ushort4 r; r.x = f2bf(v.x); r.y = f2bf(v.y); r.z = f2bf(v.z); r.w = f2bf(v.w); return r;
}
__device__ __forceinline__ float sigf(float x) { return 1.f / (1.f + __expf(-x)); }
__device__ __forceinline__ float tanhf_(float x) { return 2.f / (1.f + __expf(-2.f * x)) - 1.f; }

union U8 { unsigned long long u; ushort4 s; uint2 w; };

// coherent (IC-routed) accesses: relaxed agent atomics -> no cache inv/wb anywhere
__device__ __forceinline__ void st_flag(int* p, int v) {
  __hip_atomic_store(p, v, __ATOMIC_RELAXED, __HIP_MEMORY_SCOPE_AGENT);
}
__device__ __forceinline__ int ld_flag(const int* p) {
  return __hip_atomic_load(p, __ATOMIC_RELAXED, __HIP_MEMORY_SCOPE_AGENT);
}
__device__ __forceinline__ unsigned long long ld8(const void* p) {
  return __hip_atomic_load((const unsigned long long*)p, __ATOMIC_RELAXED, __HIP_MEMORY_SCOPE_AGENT);
}
__device__ __forceinline__ void st4(void* p, uint32 v) {
  __hip_atomic_store((uint32*)p, v, __ATOMIC_RELAXED, __HIP_MEMORY_SCOPE_AGENT);
}
__device__ __forceinline__ uint4 ld16c(const UST* p) {
  U8 a, b; a.u = ld8(p); b.u = ld8(p + 4);
  uint4 v; v.x = a.w.x; v.y = a.w.y; v.z = b.w.x; v.w = b.w.y; return v;
}

// drain own vmem (atomic stores acked at coherence point), then block-wide sync, then flag
__device__ __forceinline__ void signal_flag(int* fl, int idx, int val, int tid) {
  __atomic_signal_fence(__ATOMIC_SEQ_CST);
  __builtin_amdgcn_s_waitcnt(0);
  __atomic_signal_fence(__ATOMIC_SEQ_CST);
  __syncthreads();
  if (tid == 0) st_flag(&fl[idx * 16], val);
}
// all-to-all wait: thread t polls flag of block t (128 participants).
// Deadline-bounded: past `dl` (s_memrealtime ticks) the wait falls through so a
// protocol bug yields a fast wrong answer instead of a dead container.
__device__ __forceinline__ void wait128f(int* fl, int val, int tid, unsigned long long dl) {
  if (tid < 128) {
    while (ld_flag(&fl[tid * 16]) < val) {
      if (__builtin_amdgcn_s_memrealtime() > dl) break;
      __builtin_amdgcn_s_sleep(1);
    }
  }
  __syncthreads();
}

struct Args {
  const float* lf; const int* ulen; const int* tr; const float* emb;
  const float* wih0; const float* whh0; const float* bih0; const float* bhh0;
  const float* wih1; const float* whh1; const float* bih1; const float* bhh1;
  const float* wih2; const float* whh2; const float* bih2; const float* bhh2;
  const float* phi_w; const float* phi_b; const float* key_w; const float* key_b;
  const float* val_w; const float* val_b; const float* out_w; const float* out_b;
  const float* ihx0; const float* icx0; const float* ihx1; const float* icx1;
  const float* ihx2; const float* icx2;
  int* bar; UST* wr; UST* xemb; UST* phi_bf; UST* keyfT; UST* valfT;
  UST* hx0; UST* hx1; UST* hx2; UST* ctx; UST* h2h; UST* cxh;
  float* out_logits; float* out_attn;
};

// ---------------- P1: zero flags, fragment-linear bf16 weights, xemb, phi_bf
// weight flat idx q: i=q&7 lane=(q>>3)&63 nt=(q>>9)&1 ks=(q>>10)&31 js=(q>>15)&63 cell=q>>21
// element = W[gr = js*32+nt*16+(lane&15)][k = ks*32+(lane>>4)*8+i], gate-row gr = j*4+g
// cell0 x layout: [emb 0..383 | h0 384..895 | ctx 896..1023]
__global__ void __launch_bounds__(256) kprep(Args A) {
  const long N0 = 8192;             // flag ints (32768 B)
  const long N1 = 3L * 2048 * 1024; // weights
  const long N2 = 200L * 128 * 384; // xemb
  const long N3 = 128L * 512;       // phi
  long total = N0 + N1 + N2 + N3;
  long stride = (long)gridDim.x * blockDim.x;
  for (long ii = (long)blockIdx.x * 256 + threadIdx.x; ii < total; ii += stride) {
    long j = ii;
    if (j < N0) { A.bar[j] = 0; continue; }
    j -= N0;
    if (j < N1) {
      int q = (int)j;
      int i = q & 7, lane = (q >> 3) & 63, nt = (q >> 9) & 1, ks = (q >> 10) & 31;
      int js = (q >> 15) & 63, cell = q >> 21;
      int gr = js * 32 + nt * 16 + (lane & 15);
      int jc = gr >> 2, g = gr & 3, k = ks * 32 + (lane >> 4) * 8 + i;
      const float* wi = cell == 0 ? A.wih0 : cell == 1 ? A.wih1 : A.wih2;
      const float* wh = cell == 0 ? A.whh0 : cell == 1 ? A.whh1 : A.whh2;
      float v;
      if (cell == 0)
        v = (k < 384) ? wi[(g * 512 + jc) * 512 + k]
          : (k < 896) ? wh[(g * 512 + jc) * 512 + k - 384]
                      : wi[(g * 512 + jc) * 512 + k - 512];
      else
        v = (k < 512) ? wi[(g * 512 + jc) * 512 + k] : wh[(g * 512 + jc) * 512 + k - 512];
      A.wr[j] = f2bf(v);
      continue;
    }
    j -= N1;
    if (j < N2) {
      int t = (int)(j / 49152); int r = (int)(j % 49152); int bb = r / 384; int e = r - bb * 384;
      int ch = (t == 0) ? 0 : A.tr[(t - 1) * 128 + bb];
      A.xemb[j] = f2bf(A.emb[ch * 384 + e]);
      continue;
    }
    j -= N2;
    A.phi_bf[j] = f2bf(A.phi_w[j]);
  }
}

// ---------------- P2: keyfT/valfT = (lf . W^T + b), stored [B][C][L] bf16
__global__ void __launch_bounds__(256) kkv(Args A) {
  __shared__ __attribute__((aligned(16))) char sm[17408 + 34816];
  UST (*A_lds)[136] = (UST(*)[136])sm;
  UST (*W_lds)[136] = (UST(*)[136])(sm + 17408);
  float* sbuf = (float*)(sm + 17408);
  int tid = threadIdx.x, lane = tid & 63, wv = tid >> 6, ln = lane & 15, qd = lane >> 4;
  int blk = blockIdx.x;
  int b = blk >> 4, lt = (blk >> 1) & 7, kv = blk & 1;
  int l0 = lt * 64;
  const float* W = kv ? A.val_w : A.key_w;
  const float* bs = kv ? A.val_b : A.key_b;
  UST* outp = kv ? A.valfT : A.keyfT;
  f32x4 acc[8];
#pragma unroll
  for (int nt = 0; nt < 8; ++nt) {
    float x = bs[nt * 16 + ln];
    f32x4 t; t[0] = x; t[1] = x; t[2] = x; t[3] = x; acc[nt] = t;
  }
  for (int cc = 0; cc < 4; ++cc) {
    int d0 = cc * 128;
#pragma unroll
    for (int it = 0; it < 8; ++it) {
      int idx = it * 256 + tid, row = idx >> 5, seg = idx & 31;
      float4 v = *(const float4*)(A.lf + ((size_t)(l0 + row) * 128 + b) * 512 + d0 + seg * 4);
      *(ushort4*)&A_lds[row][seg * 4] = f2bf4(v);
    }
#pragma unroll
    for (int it = 0; it < 16; ++it) {
      int idx = it * 256 + tid, row = idx >> 5, seg = idx & 31;
      float4 v = *(const float4*)(W + (size_t)row * 512 + d0 + seg * 4);
      *(ushort4*)&W_lds[row][seg * 4] = f2bf4(v);
    }
    __syncthreads();
#pragma unroll
    for (int ks = 0; ks < 4; ++ks) {
      s16x8 av = *(const s16x8*)&A_lds[wv * 16 + ln][ks * 32 + qd * 8];
#pragma unroll
      for (int nt = 0; nt < 8; ++nt) {
        s16x8 bv = *(const s16x8*)&W_lds[nt * 16 + ln][ks * 32 + qd * 8];
        acc[nt] = __builtin_amdgcn_mfma_f32_16x16x32_bf16(av, bv, acc[nt], 0, 0, 0);
      }
    }
    __syncthreads();
  }
#pragma unroll
  for (int nt = 0; nt < 8; ++nt)
#pragma unroll
    for (int r = 0; r < 4; ++r)
      sbuf[(wv * 16 + qd * 4 + r) * 128 + nt * 16 + ln] = acc[nt][r];
  __syncthreads();
  int c2 = tid >> 1, lh = tid & 1;
  for (int g8 = 0; g8 < 4; ++g8) {
    UST tmp[8];
#pragma unroll
    for (int i = 0; i < 8; ++i) tmp[i] = f2bf(sbuf[(lh * 32 + g8 * 8 + i) * 128 + c2]);
    *(uint4*)(outp + ((size_t)b * 128 + c2) * 512 + l0 + lh * 32 + g8 * 8) = *(uint4*)tmp;
  }
}

// ---------------- cell staging: X is 64 rows x 256 k (one K-quarter), 16B chunks XOR-swizzled
// global chunk gc in [0,128); quarter q covers gc = q*32 .. q*32+31
__device__ __forceinline__ void stage0q(int tid, int q, const UST* xe, const UST* h0,
                                        const UST* cx, UST (*X)[256]) {
  __syncthreads();
#pragma unroll
  for (int it = 0; it < 8; ++it) {
    int cid = it * 256 + tid; int r = cid >> 5, c = cid & 31; int gc = q * 32 + c;
    uint4 v;
    if (gc < 48)       v = *(const uint4*)(xe + r * 384 + gc * 8);
    else if (gc < 112) v = ld16c(h0 + r * 512 + (gc - 48) * 8);
    else               v = ld16c(cx + r * 128 + (gc - 112) * 8);
    *(uint4*)&X[r][(c ^ (r & 7)) * 8] = v;
  }
}
__device__ __forceinline__ void stage12q(int tid, int q, const UST* s0, const UST* s1,
                                         UST (*X)[256]) {
  __syncthreads();
#pragma unroll
  for (int it = 0; it < 8; ++it) {
    int cid = it * 256 + tid; int r = cid >> 5, c = cid & 31; int gc = q * 32 + c;
    uint4 v = (gc < 64) ? ld16c(s0 + r * 512 + gc * 8) : ld16c(s1 + r * 512 + (gc - 64) * 8);
    *(uint4*)&X[r][(c ^ (r & 7)) * 8] = v;
  }
}
// waves split K: wave w covers local K32-slices w*2, w*2+1 of this quarter
__device__ __forceinline__ void compute_q(int w, int ln, int qd, int lane,
    const UST* wb, int q, UST (*X)[256], f32x4 acc[4][2]) {
#pragma unroll
  for (int j = 0; j < 2; ++j) {
    int ls = w * 2 + j;
    int ksg = q * 8 + ls;
    s16x8 b0 = *(const s16x8*)(wb + ((size_t)(ksg * 2 + 0) * 64 + lane) * 8);
    s16x8 b1 = *(const s16x8*)(wb + ((size_t)(ksg * 2 + 1) * 64 + lane) * 8);
#pragma unroll
    for (int rt = 0; rt < 4; ++rt) {
      int r = rt * 16 + ln, c = ls * 4 + qd;
      s16x8 av = *(const s16x8*)&X[r][(c ^ (r & 7)) * 8];
      acc[rt][0] = __builtin_amdgcn_mfma_f32_16x16x32_bf16(av, b0, acc[rt][0], 0, 0, 0);
      acc[rt][1] = __builtin_amdgcn_mfma_f32_16x16x32_bf16(av, b1, acc[rt][1], 0, 0, 0);
    }
  }
}
__device__ __forceinline__ void zacc(f32x4 acc[4][2]) {
#pragma unroll
  for (int rt = 0; rt < 4; ++rt)
#pragma unroll
    for (int nt = 0; nt < 2; ++nt) {
      acc[rt][nt][0] = 0.f; acc[rt][nt][1] = 0.f; acc[rt][nt][2] = 0.f; acc[rt][nt][3] = 0.f;
    }
}
// cross-wave K-reduce in LDS + gate nonlinearity + coherent h store
__device__ __forceinline__ void cell_epilogue(const Args& A, int cell, int t, int m, int j0,
    int tid, int w, int ln, int qd, f32x4 acc[4][2], float* FB,
    const float* bias8, float* cr, UST* hdst) {
  __syncthreads();
#pragma unroll
  for (int rt = 0; rt < 4; ++rt)
#pragma unroll
    for (int nt = 0; nt < 2; ++nt)
#pragma unroll
      for (int reg = 0; reg < 4; ++reg)
        FB[w * 2112 + (rt * 16 + qd * 4 + reg) * 33 + nt * 16 + ln] = acc[rt][nt][reg];
  __syncthreads();
  int row = tid >> 2, q4 = tid & 3, grow = m * 64 + row;
  uint32 upack = 0;
#pragma unroll
  for (int jj = 0; jj < 2; ++jj) {
    int gc = (q4 * 2 + jj) * 4;
    int o = row * 33 + gc;
    float g0 = FB[o] + FB[2112 + o] + FB[4224 + o] + FB[6336 + o] + bias8[jj * 4 + 0];
    float g1 = FB[o + 1] + FB[2112 + o + 1] + FB[4224 + o + 1] + FB[6336 + o + 1] + bias8[jj * 4 + 1];
    float g2 = FB[o + 2] + FB[2112 + o + 2] + FB[4224 + o + 2] + FB[6336 + o + 2] + bias8[jj * 4 + 2];
    float g3 = FB[o + 3] + FB[2112 + o + 3] + FB[4224 + o + 3] + FB[6336 + o + 3] + bias8[jj * 4 + 3];
    float cn = sigf(g1) * cr[jj] + sigf(g0) * tanhf_(g2);
    float hv = sigf(g3) * tanhf_(cn);
    cr[jj] = cn;
    upack |= ((uint32)f2bf(hv)) << (16 * jj);
  }
  st4(hdst + grow * 512 + j0 + q4 * 2, upack);
  if (cell == 2) *(uint32*)(A.h2h + ((size_t)t * 128 + grow) * 512 + j0 + q4 * 2) = upack;
}

// ---------------- attention (blocks 128..255, one batch row each)
__device__ void attend_f(const Args& A, int t, int p, int b, int tid, int lane, int wv,
                         char* smraw) {
  float* att_h = (float*)smraw;                       // 512
  float* att_q = att_h + 512;                         // 256
  float* att_c = att_q + 256;                         // 128
  float* att_red = att_c + 128;                       // 16
  float (*e_part)[512] = (float(*)[512])(att_red + 16);
  const UST* hx2p = A.hx2 + p * 65536;
  if (tid < 128) {
    U8 v; v.u = ld8(hx2p + b * 512 + tid * 4);
    att_h[tid * 4 + 0] = b2f(v.s.x); att_h[tid * 4 + 1] = b2f(v.s.y);
    att_h[tid * 4 + 2] = b2f(v.s.z); att_h[tid * 4 + 3] = b2f(v.s.w);
  }
  __syncthreads();
  int c = tid & 127, half = tid >> 7;
  { // q = phi_b + phi . hx2
    float acc = half ? 0.f : A.phi_b[c];
    const UST* pr = A.phi_bf + c * 512 + half * 256;
    const float* hh = att_h + half * 256;
#pragma unroll 4
    for (int k = 0; k < 256; k += 8) {
      uint4 v = *(const uint4*)(pr + k);
      const UST* us = (const UST*)&v;
#pragma unroll
      for (int i = 0; i < 8; ++i) acc += b2f(us[i]) * hh[k + i];
    }
    att_q[tid] = acc;
  }
  __syncthreads();
  if (tid < 128) att_q[tid] += att_q[tid + 128];
  __syncthreads();
  { // energies
    int cg = tid >> 6, lg = tid & 63;
    float ep[8] = {0, 0, 0, 0, 0, 0, 0, 0};
    const UST* kb = A.keyfT + (size_t)b * 65536 + lg * 8;
#pragma unroll 4
    for (int c2 = cg * 32; c2 < cg * 32 + 32; ++c2) {
      uint4 v = *(const uint4*)(kb + (size_t)c2 * 512);
      const UST* us = (const UST*)&v;
      float qv = att_q[c2];
#pragma unroll
      for (int i = 0; i < 8; ++i) ep[i] += qv * b2f(us[i]);
    }
#pragma unroll
    for (int i = 0; i < 8; ++i) e_part[cg][lg * 8 + i] = ep[i];
  }
  __syncthreads();
  float e0 = e_part[0][2 * tid] + e_part[1][2 * tid] + e_part[2][2 * tid] + e_part[3][2 * tid];
  float e1 = e_part[0][2 * tid + 1] + e_part[1][2 * tid + 1] + e_part[2][2 * tid + 1] + e_part[3][2 * tid + 1];
  float mx = fmaxf(e0, e1);
#pragma unroll
  for (int off = 32; off; off >>= 1) mx = fmaxf(mx, __shfl_xor(mx, off));
  if (lane == 0) att_red[wv] = mx;
  __syncthreads();
  mx = fmaxf(fmaxf(att_red[0], att_red[1]), fmaxf(att_red[2], att_red[3]));
  int len = A.ulen[b];
  float x0 = (2 * tid < len) ? __expf(e0 - mx) : 0.f;
  float x1 = (2 * tid + 1 < len) ? __expf(e1 - mx) : 0.f;
  float s = x0 + x1;
#pragma unroll
  for (int off = 32; off; off >>= 1) s += __shfl_xor(s, off);
  if (lane == 0) att_red[8 + wv] = s;
  __syncthreads();
  s = att_red[8] + att_red[9] + att_red[10] + att_red[11];
  float inv = 1.f / fmaxf(s, 1e-12f);
  float a0 = x0 * inv, a1 = x1 * inv;
  float* esm = &e_part[0][0];
  esm[2 * tid] = a0; esm[2 * tid + 1] = a1;
  if (t >= 0) {
    float2 st; st.x = a0; st.y = a1;
    *(float2*)(A.out_attn + ((size_t)t * 128 + b) * 512 + 2 * tid) = st;
  }
  __syncthreads();
  { // ctx[c] = sum_l a_l * valfT[b][c][l]
    float acc = 0.f;
    const UST* vb = A.valfT + (size_t)b * 65536 + (size_t)c * 512 + half * 256;
    const float* aa = esm + half * 256;
#pragma unroll 4
    for (int k = 0; k < 256; k += 8) {
      uint4 v = *(const uint4*)(vb + k);
      const UST* us = (const UST*)&v;
#pragma unroll
      for (int i = 0; i < 8; ++i) acc += aa[k + i] * b2f(us[i]);
    }
    att_q[tid] = acc;
  }
  __syncthreads();
  if (tid < 128) att_c[tid] = att_q[tid] + att_q[tid + 128];
  __syncthreads();
  if (tid < 64) {
    float cv0 = att_c[2 * tid], cv1 = att_c[2 * tid + 1];
    uint32 u = (uint32)f2bf(cv0) | ((uint32)f2bf(cv1) << 16);
    st4(A.ctx + p * 16384 + b * 128 + 2 * tid, u);
    if (t >= 0) *(uint32*)(A.cxh + ((size_t)t * 128 + b) * 128 + 2 * tid) = u;
  }
}

// ---------------- main persistent kernel. PLAIN launch (not cooperative): sync is
// hand-rolled flags; co-residency guaranteed by capacity arithmetic (LDS 36,864 B -> 4
// blocks/CU; even worst-case VGPR >256 gives 1 block/CU x 256 CUs = grid size).
// All waits are deadline-bounded (~1 s) so any protocol bug terminates instead of
// hanging the container.
__global__ void __launch_bounds__(256) kmain(Args A) {
  __shared__ __attribute__((aligned(16))) char smraw[36864];
  unsigned long long dl = __builtin_amdgcn_s_memrealtime() + 100000000ull;
  int blk = blockIdx.x, tid = threadIdx.x;
  int lane = tid & 63, w = tid >> 6, ln = lane & 15, qd = lane >> 4;
  int* c0f = A.bar;
  int* c1f = A.bar + 2048;
  int* c2f = A.bar + 4096;
  int* attf = A.bar + 6144;
  if (blk < 128) {
    UST (*X)[256] = (UST(*)[256])smraw;   // 32 KB quarter-K staging
    float* FB = (float*)smraw;            // 33,792 B epilogue reduce (aliased)
    // same-XCD weight-slab pairing: blk and blk^8 share js and land on one XCD
    int js = ((blk >> 4) << 3) | (blk & 7);
    int m = (blk >> 3) & 1;
    int j0 = js * 8;
    float bias[3][8]; float cr[3][2];
    {
      const float* bihA[3] = {A.bih0, A.bih1, A.bih2};
      const float* bhhA[3] = {A.bhh0, A.bhh1, A.bhh2};
      const float* icxA[3] = {A.icx0, A.icx1, A.icx2};
      const float* ihxA[3] = {A.ihx0, A.ihx1, A.ihx2};
      UST* hxA[3] = {A.hx0, A.hx1, A.hx2};
      int q4 = tid & 3;
#pragma unroll
      for (int cI = 0; cI < 3; ++cI) {
#pragma unroll
        for (int jj = 0; jj < 2; ++jj) {
          int col = j0 + q4 * 2 + jj;
          for (int g = 0; g < 4; ++g)
            bias[cI][jj * 4 + g] = bihA[cI][g * 512 + col] + bhhA[cI][g * 512 + col];
          cr[cI][jj] = icxA[cI][col];
        }
        int row = tid >> 2, grow = m * 64 + row, col0 = j0 + q4 * 2;
        uint32 u = (uint32)f2bf(ihxA[cI][col0]) | ((uint32)f2bf(ihxA[cI][col0 + 1]) << 16);
        st4(hxA[cI] + 65536 + grow * 512 + col0, u);  // init into slot 1
      }
    }
    signal_flag(c2f, blk, 1, tid);
    wait128f(c2f, 1, tid, dl);
    const UST* wrj = A.wr + (size_t)js * 32768;
    f32x4 acc[4][2];
    for (int t = 0; t < 200; ++t) {
      int p = t & 1, po = p ^ 1;
      const UST* xe = A.xemb + (size_t)t * 49152 + m * 64 * 384;
      const UST* h0r = A.hx0 + po * 65536 + m * 64 * 512;
      const UST* h1r = A.hx1 + po * 65536 + m * 64 * 512;
      const UST* h2r = A.hx2 + po * 65536 + m * 64 * 512;
      const UST* cxr = A.ctx + po * 16384 + m * 64 * 128;
      // ---- cell0: quarters 0..2 (emb+h0) overlap attend; quarter 3 (h0 tail+ctx) after att flag
      zacc(acc);
      stage0q(tid, 0, xe, h0r, cxr, X); __syncthreads();
      compute_q(w, ln, qd, lane, wrj, 0, X, acc);
      stage0q(tid, 1, xe, h0r, cxr, X); __syncthreads();
      compute_q(w, ln, qd, lane, wrj, 1, X, acc);
      stage0q(tid, 2, xe, h0r, cxr, X); __syncthreads();
      compute_q(w, ln, qd, lane, wrj, 2, X, acc);
      wait128f(attf, t + 1, tid, dl);
      stage0q(tid, 3, xe, h0r, cxr, X); __syncthreads();
      compute_q(w, ln, qd, lane, wrj, 3, X, acc);
      cell_epilogue(A, 0, t, m, j0, tid, w, ln, qd, acc, FB, bias[0], cr[0], A.hx0 + p * 65536);
      signal_flag(c0f, blk, t + 2, tid);
      wait128f(c0f, t + 2, tid, dl);
      // ---- cell1: x = [h0(t) | h1(t-1)]
      const UST* h0n = A.hx0 + p * 65536 + m * 64 * 512;
      zacc(acc);
#pragma unroll
      for (int q = 0; q < 4; ++q) {
        stage12q(tid, q, h0n, h1r, X); __syncthreads();
        compute_q(w, ln, qd, lane, wrj + 2097152, q, X, acc);
      }
      cell_epilogue(A, 1, t, m, j0, tid, w, ln, qd, acc, FB, bias[1], cr[1], A.hx1 + p * 65536);
      signal_flag(c1f, blk, t + 2, tid);
      wait128f(c1f, t + 2, tid, dl);
      // ---- cell2: x = [h1(t) | h2(t-1)]
      const UST* h1n = A.hx1 + p * 65536 + m * 64 * 512;
      zacc(acc);
#pragma unroll
      for (int q = 0; q < 4; ++q) {
        stage12q(tid, q, h1n, h2r, X); __syncthreads();
        compute_q(w, ln, qd, lane, wrj + 2 * 2097152, q, X, acc);
      }
      cell_epilogue(A, 2, t, m, j0, tid, w, ln, qd, acc, FB, bias[2], cr[2], A.hx2 + p * 65536);
      signal_flag(c2f, blk, t + 2, tid);
      // no wait: next iteration's early staging needs only h0(t) (synced at c0-wait)
    }
  } else {
    int b = blk - 128;
    wait128f(c2f, 1, tid, dl);
    attend_f(A, -1, 1, b, tid, lane, w, smraw);
    signal_flag(attf, b, 1, tid);
    for (int t = 0; t < 200; ++t) {
      wait128f(c2f, t + 2, tid, dl);
      attend_f(A, t, t & 1, b, tid, lane, w, smraw);
      signal_flag(attf, b, t + 2, tid);
    }
  }
}

// ---------------- epilogue: logits[t,b,v] = [hx2,ctx] . out_w^T + out_b
__global__ void __launch_bounds__(256) kepi(Args A) {
  __shared__ UST ow[46 * 648];
  __shared__ float ob[46];
  int t = blockIdx.x, tid = threadIdx.x;
  for (int i = tid; i < 46 * 640; i += 256) {
    int v = i / 640, k = i - v * 640; ow[v * 648 + k] = f2bf(A.out_w[i]);
  }
  if (tid < 46) ob[tid] = A.out_b[tid];
  __syncthreads();
  for (int oi = tid; oi < 128 * 46; oi += 256) {
    int bb = oi / 46, v = oi - bb * 46;
    const UST* xh = A.h2h + ((size_t)t * 128 + bb) * 512;
    const UST* xc = A.cxh + ((size_t)t * 128 + bb) * 128;
    const UST* wrow = &ow[v * 648];
    float acc = ob[v];
    for (int k = 0; k < 512; k += 8) {
      uint4 xv = *(const uint4*)(xh + k);
      uint4 wv4 = *(const uint4*)(wrow + k);
      const UST* xs = (const UST*)&xv; const UST* wl = (const UST*)&wv4;
#pragma unroll
      for (int i = 0; i < 8; ++i) acc += b2f(xs[i]) * b2f(wl[i]);
    }
    for (int k = 0; k < 128; k += 8) {
      uint4 xv = *(const uint4*)(xc + k);
      uint4 wv4 = *(const uint4*)(wrow + 512 + k);
      const UST* xs = (const UST*)&xv; const UST* wl = (const UST*)&wv4;
#pragma unroll
      for (int i = 0; i < 8; ++i) acc += b2f(xs[i]) * b2f(wl[i]);
    }
    A.out_logits[((size_t)t * 128 + bb) * 46 + v] = acc;
  }
}

extern "C" void kernel_launch(void* const* d_in, const int* in_sizes, int n_in,
                              void* d_out, int out_size, void* d_ws, size_t ws_size,
                              hipStream_t stream) {
  (void)in_sizes; (void)n_in; (void)out_size; (void)ws_size;
  Args a;
  a.lf = (const float*)d_in[0]; a.ulen = (const int*)d_in[1]; a.tr = (const int*)d_in[2];
  a.emb = (const float*)d_in[3];
  a.wih0 = (const float*)d_in[4]; a.whh0 = (const float*)d_in[5]; a.bih0 = (const float*)d_in[6]; a.bhh0 = (const float*)d_in[7];
  a.wih1 = (const float*)d_in[8]; a.whh1 = (const float*)d_in[9]; a.bih1 = (const float*)d_in[10]; a.bhh1 = (const float*)d_in[11];
  a.wih2 = (const float*)d_in[12]; a.whh2 = (const float*)d_in[13]; a.bih2 = (const float*)d_in[14]; a.bhh2 = (const float*)d_in[15];
  a.phi_w = (const float*)d_in[16]; a.phi_b = (const float*)d_in[17];
  a.key_w = (const float*)d_in[18]; a.key_b = (const float*)d_in[19];
  a.val_w = (const float*)d_in[20]; a.val_b = (const float*)d_in[21];
  a.out_w = (const float*)d_in[22]; a.out_b = (const float*)d_in[23];
  a.ihx0 = (const float*)d_in[24]; a.icx0 = (const float*)d_in[25];
  a.ihx1 = (const float*)d_in[26]; a.icx1 = (const float*)d_in[27];
  a.ihx2 = (const float*)d_in[28]; a.icx2 = (const float*)d_in[29];
  char* ws = (char*)d_ws;
  a.bar    = (int*)ws;                   // 32,768 B (4 flag arrays x 128 x 16 ints)
  a.wr     = (UST*)(ws + 32768);         // 12,582,912 B
  a.xemb   = (UST*)(ws + 12615680);      // 19,660,800 B
  a.phi_bf = (UST*)(ws + 32276480);      // 131,072 B
  a.keyfT  = (UST*)(ws + 32407552);      // 16,777,216 B
  a.valfT  = (UST*)(ws + 49184768);      // 16,777,216 B
  a.hx0    = (UST*)(ws + 65961984);      // 262,144 B (2 slots)
  a.hx1    = (UST*)(ws + 66224128);      // 262,144 B
  a.hx2    = (UST*)(ws + 66486272);      // 262,144 B
  a.ctx    = (UST*)(ws + 66748416);      // 65,536 B (2 slots)
  a.h2h    = (UST*)(ws + 66813952);      // 26,214,400 B
  a.cxh    = (UST*)(ws + 93028352);      // 6,553,600 B -> total 99,581,952 B
  a.out_logits = (float*)d_out;
  a.out_attn   = (float*)d_out + 1177600;
  kprep<<<4096, 256, 0, stream>>>(a);
  kkv<<<2048, 256, 0, stream>>>(a);
  kmain<<<256, 256, 0, stream>>>(a);
  kepi<<<200, 256, 0, stream>>>(a);
}